// Round 2
// baseline (253.226 us; speedup 1.0000x reference)
//
#include <hip/hip_runtime.h>
#include <hip/hip_bf16.h>
#include <math.h>

typedef __bf16 bf16_t;
typedef __bf16 bf16x8 __attribute__((ext_vector_type(8)));
typedef float f32x4 __attribute__((ext_vector_type(4)));

#define BATCH 131072
#define MTILE 64
#define NBLK (BATCH / MTILE)

// fragment-layout weight offsets in d_ws (elements, bf16) — hi plane
#define W1F 0
#define W2F 4096
#define W3F 20480
#define W4F 36864
#define WFRAG 135168   // elements per plane; lo plane at +WFRAG

// ---------------------------------------------------------------------------
// Kernel A: fp32 weights -> bf16 hi/lo MFMA B-fragment planes.
// B-frag (mfma_f32_16x16x32_bf16): lane holds 8 contiguous-k bf16:
//   col = tile*16 + (lane&15), k = kstep*32 + (lane>>4)*8 + j
// W4 laid out as 8 chunks x 92 cols padded to 96 (6 tiles).
// ---------------------------------------------------------------------------
__global__ __launch_bounds__(256) void convert_weights_kernel(
    const float* __restrict__ W1, const float* __restrict__ W2,
    const float* __restrict__ W3, const float* __restrict__ W4,
    bf16_t* __restrict__ wf) {
  int tid = blockIdx.x * 256 + threadIdx.x;
  if (tid >= 16896) return;
  int lane = tid & 63;
  int l16 = lane & 15, lhi = lane >> 4;
  const float* W; int ncols, col, k0; bool zero = false;
  if (tid < 512) {                       // W1: 8 n-tiles, K=32 (1 step)
    int n = tid >> 6;
    W = W1; ncols = 128; col = n * 16 + l16; k0 = lhi * 8;
  } else if (tid < 2560) {               // W2: 8 n-tiles x 4 k-steps
    int g = tid - 512; int n = g >> 8, s = (g >> 6) & 3;
    W = W2; ncols = 128; col = n * 16 + l16; k0 = s * 32 + lhi * 8;
  } else if (tid < 4608) {               // W3
    int g = tid - 2560; int n = g >> 8, s = (g >> 6) & 3;
    W = W3; ncols = 128; col = n * 16 + l16; k0 = s * 32 + lhi * 8;
  } else {                               // W4: 8 chunks x 6 n-tiles x 4 k-steps
    int g = tid - 4608; int t = g >> 8, s = (g >> 6) & 3;
    int c = t / 6, n = t - c * 6;
    int colc = n * 16 + l16;
    W = W4; ncols = 736; col = c * 92 + colc; k0 = s * 32 + lhi * 8;
    zero = (colc >= 92);
  }
  bf16x8 vh, vl;
#pragma unroll
  for (int j = 0; j < 8; ++j) {
    float v = zero ? 0.f : W[(k0 + j) * ncols + col];
    bf16_t h = (bf16_t)v;
    vh[j] = h;
    vl[j] = (bf16_t)(v - (float)h);
  }
  *(bf16x8*)(wf + (size_t)tid * 8) = vh;
  *(bf16x8*)(wf + WFRAG + (size_t)tid * 8) = vl;
}

// ---------------------------------------------------------------------------
// split 8 contiguous fp32 (LDS) into hi/lo bf16x8 fragments
// ---------------------------------------------------------------------------
__device__ __forceinline__ void split8(const float* p, bf16x8& hi, bf16x8& lo) {
#pragma unroll
  for (int j = 0; j < 8; ++j) {
    float v = p[j];
    bf16_t h = (bf16_t)v;
    hi[j] = h;
    lo[j] = (bf16_t)(v - (float)h);
  }
}

// triple-MFMA split-precision accumulate
__device__ __forceinline__ f32x4 mfma3(bf16x8 ah, bf16x8 al, bf16x8 bh, bf16x8 bl,
                                       f32x4 acc) {
  acc = __builtin_amdgcn_mfma_f32_16x16x32_bf16(ah, bh, acc, 0, 0, 0);
  acc = __builtin_amdgcn_mfma_f32_16x16x32_bf16(ah, bl, acc, 0, 0, 0);
  acc = __builtin_amdgcn_mfma_f32_16x16x32_bf16(al, bh, acc, 0, 0, 0);
  return acc;
}

// ---------------------------------------------------------------------------
// middle MLP layer, in-place on the wave's own 16-row strip of hH (fp32).
// All A-fragments are register-resident before the first store -> safe.
// ---------------------------------------------------------------------------
__device__ __forceinline__ void mid_layer_ip(float* hH,
                                             const bf16_t* __restrict__ wh,
                                             const bf16_t* __restrict__ wl,
                                             const float* __restrict__ bg,
                                             int wv, int l16, int lhi, int lane) {
  bf16x8 ah[4], al[4];
#pragma unroll
  for (int s = 0; s < 4; ++s)
    split8(&hH[(wv * 16 + l16) * 132 + s * 32 + lhi * 8], ah[s], al[s]);
#pragma unroll
  for (int n = 0; n < 8; ++n) {
    f32x4 acc = {0.f, 0.f, 0.f, 0.f};
#pragma unroll
    for (int s = 0; s < 4; ++s) {
      bf16x8 bh = *(const bf16x8*)(wh + (size_t)((n * 4 + s) * 64 + lane) * 8);
      bf16x8 bl = *(const bf16x8*)(wl + (size_t)((n * 4 + s) * 64 + lane) * 8);
      acc = mfma3(ah[s], al[s], bh, bl, acc);
    }
    float bias = bg[n * 16 + l16];
#pragma unroll
    for (int r = 0; r < 4; ++r) {
      float v = acc[r] + bias;
      v = v > 0.f ? v : (__expf(v) - 1.f);   // ELU
      hH[(wv * 16 + lhi * 4 + r) * 132 + n * 16 + l16] = v;
    }
  }
}

// ---------------------------------------------------------------------------
// Kernel B: fused MLP (bf16x2 split precision) + RQS spline.
// 64 rows/block, 4 waves; each wave owns a 16-row strip.
// ---------------------------------------------------------------------------
__global__ __launch_bounds__(256, 2) void nsf_fused_kernel(
    const float* __restrict__ x,
    const float* __restrict__ b1g, const float* __restrict__ b2g,
    const float* __restrict__ b3g, const float* __restrict__ b4g,
    const bf16_t* __restrict__ wf,
    float* __restrict__ out) {
  __shared__ float hH[64 * 132];    // hidden state, fp32, in-place across layers
  __shared__ float prm[64 * 100];   // spline params chunk (4 dims x 23, stride 100)
  __shared__ float x2s[64 * 33];    // x2 tile

  const int tid = threadIdx.x;
  const int lane = tid & 63;
  const int wv = tid >> 6;
  const int l16 = lane & 15, lhi = lane >> 4;
  const int row0 = blockIdx.x * MTILE;

  const bf16_t* wfl = wf + WFRAG;   // lo plane

  // ---- stage x: x1 -> out + hH cols[0:32) (fp32), x2 -> x2s ----
  {
    const float4* x4 = (const float4*)(x + (size_t)row0 * 64);
    float4* o4 = (float4*)(out + (size_t)row0 * 64);
#pragma unroll
    for (int it = 0; it < 4; ++it) {
      int idx = tid + it * 256;          // 0..1023 = 64 rows x 16 float4
      int row = idx >> 4, q = idx & 15;
      float4 v = x4[row * 16 + q];
      if (q < 8) {                       // x1 cols 0..31
        o4[row * 16 + q] = v;
        *(float4*)&hH[row * 132 + q * 4] = v;
      } else {                           // x2 cols 32..63
        int cb = row * 33 + (q - 8) * 4;
        x2s[cb + 0] = v.x; x2s[cb + 1] = v.y;
        x2s[cb + 2] = v.z; x2s[cb + 3] = v.w;
      }
    }
  }
  __syncthreads();

  // ---- layer 1: (64x32)@(32x128), K=32, in-place ----
  {
    bf16x8 ah, al;
    split8(&hH[(wv * 16 + l16) * 132 + lhi * 8], ah, al);
#pragma unroll
    for (int n = 0; n < 8; ++n) {
      bf16x8 bh = *(const bf16x8*)(wf + W1F + (size_t)(n * 64 + lane) * 8);
      bf16x8 bl = *(const bf16x8*)(wfl + W1F + (size_t)(n * 64 + lane) * 8);
      f32x4 acc = {0.f, 0.f, 0.f, 0.f};
      acc = mfma3(ah, al, bh, bl, acc);
      float bias = b1g[n * 16 + l16];
#pragma unroll
      for (int r = 0; r < 4; ++r) {
        float v = acc[r] + bias;
        v = v > 0.f ? v : (__expf(v) - 1.f);
        hH[(wv * 16 + lhi * 4 + r) * 132 + n * 16 + l16] = v;
      }
    }
  }
  // no sync needed: each wave reads/writes only its own strip

  mid_layer_ip(hH, wf + W2F, wfl + W2F, b2g, wv, l16, lhi, lane);   // layer 2
  mid_layer_ip(hH, wf + W3F, wfl + W3F, b3g, wv, l16, lhi, lane);   // layer 3

  // ---- layer 4 + spline, 8 chunks of 4 spline-dims each ----
  {
    bf16x8 a4h[4], a4l[4];
#pragma unroll
    for (int s = 0; s < 4; ++s)
      split8(&hH[(wv * 16 + l16) * 132 + s * 32 + lhi * 8], a4h[s], a4l[s]);

    const int srow = tid >> 2;   // spline row 0..63
    const int sjj = tid & 3;     // chunk-local spline dim
    float ldp = 0.f;

    for (int c = 0; c < 8; ++c) {
      // GEMM4 chunk: 92 real cols (4 dims x 23) padded to 96 (6 tiles)
#pragma unroll
      for (int n = 0; n < 6; ++n) {
        f32x4 acc = {0.f, 0.f, 0.f, 0.f};
#pragma unroll
        for (int s = 0; s < 4; ++s) {
          size_t off = (size_t)(((c * 6 + n) * 4 + s) * 64 + lane) * 8;
          bf16x8 bh = *(const bf16x8*)(wf + W4F + off);
          bf16x8 bl = *(const bf16x8*)(wfl + W4F + off);
          acc = mfma3(a4h[s], a4l[s], bh, bl, acc);
        }
        int colc = n * 16 + l16;
        if (colc < 92) {
          float bias = b4g[c * 92 + colc];
#pragma unroll
          for (int r = 0; r < 4; ++r)
            prm[(wv * 16 + lhi * 4 + r) * 100 + colc] = acc[r] + bias;
        }
      }
      __syncthreads();

      // ---- spline: one (row, dim) task per thread ----
      {
        const float* P = &prm[srow * 100 + sjj * 23];
        float uw[8], uh[8], ud[7];
#pragma unroll
        for (int i = 0; i < 8; ++i) uw[i] = P[i];
#pragma unroll
        for (int i = 0; i < 8; ++i) uh[i] = P[8 + i];
#pragma unroll
        for (int i = 0; i < 7; ++i) ud[i] = P[16 + i];

        // softmax widths -> cumwidths
        float mw = uw[0];
#pragma unroll
        for (int i = 1; i < 8; ++i) mw = fmaxf(mw, uw[i]);
        float ew[8], sw = 0.f;
#pragma unroll
        for (int i = 0; i < 8; ++i) { ew[i] = __expf(uw[i] - mw); sw += ew[i]; }
        float invw = 1.f / sw;
        float cw[9]; cw[0] = -3.f;
        float accw = 0.f;
#pragma unroll
        for (int i = 0; i < 8; ++i) {
          accw += 0.001f + 0.992f * ew[i] * invw;
          cw[i + 1] = -3.f + 6.f * accw;
        }
        cw[8] = 3.f;
        float wd[8];
#pragma unroll
        for (int i = 0; i < 8; ++i) wd[i] = cw[i + 1] - cw[i];

        // softmax heights -> cumheights
        float mh = uh[0];
#pragma unroll
        for (int i = 1; i < 8; ++i) mh = fmaxf(mh, uh[i]);
        float eh[8], sh = 0.f;
#pragma unroll
        for (int i = 0; i < 8; ++i) { eh[i] = __expf(uh[i] - mh); sh += eh[i]; }
        float invh = 1.f / sh;
        float ch[9]; ch[0] = -3.f;
        float acch = 0.f;
#pragma unroll
        for (int i = 0; i < 8; ++i) {
          acch += 0.001f + 0.992f * eh[i] * invh;
          ch[i + 1] = -3.f + 6.f * acch;
        }
        ch[8] = 3.f;
        float ht[8];
#pragma unroll
        for (int i = 0; i < 8; ++i) ht[i] = ch[i + 1] - ch[i];

        // derivatives: boundary pad gives exactly 1.0
        float dd[9]; dd[0] = 1.f; dd[8] = 1.f;
#pragma unroll
        for (int i = 0; i < 7; ++i) {
          float u = ud[i];
          float sp = (u > 20.f) ? u : log1pf(__expf(u));
          dd[i + 1] = 0.001f + sp;
        }

        int jg = c * 4 + sjj;
        float xv = x2s[srow * 33 + jg];
        float xc = fminf(fmaxf(xv, -3.f), 3.f);

        int bin = 0;   // count of interior cumwidths <= x
#pragma unroll
        for (int i = 1; i < 8; ++i) bin += (xc >= cw[i]) ? 1 : 0;

        // gather via unrolled select chains (static indices -> registers)
        float in_cw = cw[0], in_w = wd[0], in_ch = ch[0], in_h = ht[0];
        float in_d = dd[0], in_d1 = dd[1];
#pragma unroll
        for (int i = 1; i < 8; ++i) {
          bool g = (bin >= i);
          in_cw = g ? cw[i] : in_cw;  in_w = g ? wd[i] : in_w;
          in_ch = g ? ch[i] : in_ch;  in_h = g ? ht[i] : in_h;
          in_d  = g ? dd[i] : in_d;   in_d1 = g ? dd[i + 1] : in_d1;
        }

        float dlt = in_h / in_w;
        float th = (xc - in_cw) / in_w;
        float om = 1.f - th;
        float t1 = th * om;
        float num = in_h * (dlt * th * th + in_d * t1);
        float den = dlt + (in_d + in_d1 - 2.f * dlt) * t1;
        float yo = in_ch + num / den;
        float dn = dlt * dlt * (in_d1 * th * th + 2.f * dlt * t1 + in_d * om * om);
        float ldv = __logf(dn) - 2.f * __logf(den);
        bool inside = (xv >= -3.f) && (xv <= 3.f);
        out[(size_t)(row0 + srow) * 64 + 32 + jg] = inside ? yo : xv;
        ldp += inside ? ldv : 0.f;
      }
      __syncthreads();
    }

    // ---- log_det: quad reduce over sjj ----
    float tot = ldp;
    tot += __shfl_xor(tot, 1, 64);
    tot += __shfl_xor(tot, 2, 64);
    if ((tid & 3) == 0)
      out[(size_t)BATCH * 64 + row0 + srow] = tot;
  }
}

// ---------------------------------------------------------------------------
extern "C" void kernel_launch(void* const* d_in, const int* in_sizes, int n_in,
                              void* d_out, int out_size, void* d_ws, size_t ws_size,
                              hipStream_t stream) {
  const float* x  = (const float*)d_in[0];
  const float* W1 = (const float*)d_in[1];
  const float* b1 = (const float*)d_in[2];
  const float* W2 = (const float*)d_in[3];
  const float* b2 = (const float*)d_in[4];
  const float* W3 = (const float*)d_in[5];
  const float* b3 = (const float*)d_in[6];
  const float* W4 = (const float*)d_in[7];
  const float* b4 = (const float*)d_in[8];
  bf16_t* wf = (bf16_t*)d_ws;
  float* out = (float*)d_out;

  hipLaunchKernelGGL(convert_weights_kernel, dim3(66), dim3(256), 0, stream,
                     W1, W2, W3, W4, wf);
  hipLaunchKernelGGL(nsf_fused_kernel, dim3(NBLK), dim3(256), 0, stream,
                     x, b1, b2, b3, b4, wf, out);
}

// Round 3
// 112.863 us; speedup vs baseline: 2.2436x; 2.2436x over previous
//
#include <hip/hip_runtime.h>
#include <hip/hip_bf16.h>
#include <math.h>

typedef _Float16 f16_t;
typedef _Float16 f16x8 __attribute__((ext_vector_type(8)));
typedef float f32x4 __attribute__((ext_vector_type(4)));

#define BATCH 131072
#define MTILE 64
#define NBLK (BATCH / MTILE)

// fragment-layout weight offsets in d_ws (elements, f16)
#define W1F 0
#define W2F 4096
#define W3F 20480
#define W4F 36864
// total 135168 elements = 270336 B of d_ws

// ---------------------------------------------------------------------------
// Kernel A: fp32 weights -> fp16 MFMA B-fragment layout.
// B-frag (mfma_f32_16x16x32_f16): lane holds 8 contiguous-k f16:
//   col = tile*16 + (lane&15), k = kstep*32 + (lane>>4)*8 + j
// W4 laid out as 8 chunks x 92 cols padded to 96 (6 tiles).
// ---------------------------------------------------------------------------
__global__ __launch_bounds__(256) void convert_weights_kernel(
    const float* __restrict__ W1, const float* __restrict__ W2,
    const float* __restrict__ W3, const float* __restrict__ W4,
    f16_t* __restrict__ wf) {
  int tid = blockIdx.x * 256 + threadIdx.x;
  if (tid >= 16896) return;
  int lane = tid & 63;
  int l16 = lane & 15, lhi = lane >> 4;
  const float* W; int ncols, col, k0; bool zero = false;
  if (tid < 512) {                       // W1: 8 n-tiles, K=32 (1 step)
    int n = tid >> 6;
    W = W1; ncols = 128; col = n * 16 + l16; k0 = lhi * 8;
  } else if (tid < 2560) {               // W2: 8 n-tiles x 4 k-steps
    int g = tid - 512; int n = g >> 8, s = (g >> 6) & 3;
    W = W2; ncols = 128; col = n * 16 + l16; k0 = s * 32 + lhi * 8;
  } else if (tid < 4608) {               // W3
    int g = tid - 2560; int n = g >> 8, s = (g >> 6) & 3;
    W = W3; ncols = 128; col = n * 16 + l16; k0 = s * 32 + lhi * 8;
  } else {                               // W4: 8 chunks x 6 n-tiles x 4 k-steps
    int g = tid - 4608; int t = g >> 8, s = (g >> 6) & 3;
    int c = t / 6, n = t - c * 6;
    int colc = n * 16 + l16;
    W = W4; ncols = 736; col = c * 92 + colc; k0 = s * 32 + lhi * 8;
    zero = (colc >= 92);
  }
  f16x8 v;
#pragma unroll
  for (int j = 0; j < 8; ++j)
    v[j] = zero ? (f16_t)0.f : (f16_t)W[(k0 + j) * ncols + col];
  *(f16x8*)(wf + (size_t)tid * 8) = v;
}

// ---------------------------------------------------------------------------
// middle MLP layer, in-place on the wave's own 16-row strip of hH (fp16).
// A-fragments are register-resident before the first store (program order,
// aliasing LDS -> compiler preserves read-before-write).
// ---------------------------------------------------------------------------
__device__ __forceinline__ void mid_layer_ip(f16_t* hH,
                                             const f16_t* __restrict__ wseg,
                                             const float* __restrict__ bg,
                                             int wv, int l16, int lhi, int lane) {
  f16x8 a[4];
#pragma unroll
  for (int s = 0; s < 4; ++s)
    a[s] = *(const f16x8*)&hH[(wv * 16 + l16) * 136 + s * 32 + lhi * 8];
#pragma unroll
  for (int n = 0; n < 8; ++n) {
    f32x4 acc = {0.f, 0.f, 0.f, 0.f};
#pragma unroll
    for (int s = 0; s < 4; ++s) {
      f16x8 b = *(const f16x8*)(wseg + (size_t)((n * 4 + s) * 64 + lane) * 8);
      acc = __builtin_amdgcn_mfma_f32_16x16x32_f16(a[s], b, acc, 0, 0, 0);
    }
    float bias = bg[n * 16 + l16];
#pragma unroll
    for (int r = 0; r < 4; ++r) {
      float v = acc[r] + bias;
      v = v > 0.f ? v : (__expf(v) - 1.f);   // ELU
      hH[(wv * 16 + lhi * 4 + r) * 136 + n * 16 + l16] = (f16_t)v;
    }
  }
}

// ---------------------------------------------------------------------------
// Kernel B: fused MLP (fp16 MFMA) + RQS spline. 64 rows/block, 4 waves.
// LDS: 17408 + 25600 + 8448 = 51456 B -> 3 blocks/CU.
// ---------------------------------------------------------------------------
__global__ __launch_bounds__(256, 3) void nsf_fused_kernel(
    const float* __restrict__ x,
    const float* __restrict__ b1g, const float* __restrict__ b2g,
    const float* __restrict__ b3g, const float* __restrict__ b4g,
    const f16_t* __restrict__ wf,
    float* __restrict__ out) {
  __shared__ f16_t hH[64 * 136];    // hidden state, fp16, in-place across layers
  __shared__ float prm[64 * 100];   // spline params chunk (4 dims x 23, stride 100)
  __shared__ float x2s[64 * 33];    // x2 tile

  const int tid = threadIdx.x;
  const int lane = tid & 63;
  const int wv = tid >> 6;
  const int l16 = lane & 15, lhi = lane >> 4;
  const int row0 = blockIdx.x * MTILE;

  // ---- stage x: x1 -> out + hH cols[0:32) (fp16), x2 -> x2s ----
  {
    const float4* x4 = (const float4*)(x + (size_t)row0 * 64);
    float4* o4 = (float4*)(out + (size_t)row0 * 64);
#pragma unroll
    for (int it = 0; it < 4; ++it) {
      int idx = tid + it * 256;          // 0..1023 = 64 rows x 16 float4
      int row = idx >> 4, q = idx & 15;
      float4 v = x4[row * 16 + q];
      if (q < 8) {                       // x1 cols 0..31
        o4[row * 16 + q] = v;
        f16_t* p = &hH[row * 136 + q * 4];
        p[0] = (f16_t)v.x; p[1] = (f16_t)v.y;
        p[2] = (f16_t)v.z; p[3] = (f16_t)v.w;
      } else {                           // x2 cols 32..63
        int cb = row * 33 + (q - 8) * 4;
        x2s[cb + 0] = v.x; x2s[cb + 1] = v.y;
        x2s[cb + 2] = v.z; x2s[cb + 3] = v.w;
      }
    }
  }
  __syncthreads();

  // ---- layer 1: (64x32)@(32x128), K=32, in-place ----
  {
    f16x8 a = *(const f16x8*)&hH[(wv * 16 + l16) * 136 + lhi * 8];
#pragma unroll
    for (int n = 0; n < 8; ++n) {
      f16x8 b = *(const f16x8*)(wf + W1F + (size_t)(n * 64 + lane) * 8);
      f32x4 acc = {0.f, 0.f, 0.f, 0.f};
      acc = __builtin_amdgcn_mfma_f32_16x16x32_f16(a, b, acc, 0, 0, 0);
      float bias = b1g[n * 16 + l16];
#pragma unroll
      for (int r = 0; r < 4; ++r) {
        float v = acc[r] + bias;
        v = v > 0.f ? v : (__expf(v) - 1.f);
        hH[(wv * 16 + lhi * 4 + r) * 136 + n * 16 + l16] = (f16_t)v;
      }
    }
  }
  // no sync needed: each wave reads/writes only its own strip

  mid_layer_ip(hH, wf + W2F, b2g, wv, l16, lhi, lane);   // layer 2
  mid_layer_ip(hH, wf + W3F, b3g, wv, l16, lhi, lane);   // layer 3

  // ---- layer 4 + spline, 8 chunks of 4 spline-dims each ----
  {
    f16x8 a4[4];
#pragma unroll
    for (int s = 0; s < 4; ++s)
      a4[s] = *(const f16x8*)&hH[(wv * 16 + l16) * 136 + s * 32 + lhi * 8];

    const int srow = tid >> 2;   // spline row 0..63
    const int sjj = tid & 3;     // chunk-local spline dim
    float ldp = 0.f;

    for (int c = 0; c < 8; ++c) {
      // GEMM4 chunk: 92 real cols (4 dims x 23) padded to 96 (6 tiles)
#pragma unroll
      for (int n = 0; n < 6; ++n) {
        f32x4 acc = {0.f, 0.f, 0.f, 0.f};
#pragma unroll
        for (int s = 0; s < 4; ++s) {
          f16x8 b = *(const f16x8*)(wf + W4F +
                      (size_t)(((c * 6 + n) * 4 + s) * 64 + lane) * 8);
          acc = __builtin_amdgcn_mfma_f32_16x16x32_f16(a4[s], b, acc, 0, 0, 0);
        }
        int colc = n * 16 + l16;
        if (colc < 92) {
          float bias = b4g[c * 92 + colc];
#pragma unroll
          for (int r = 0; r < 4; ++r)
            prm[(wv * 16 + lhi * 4 + r) * 100 + colc] = acc[r] + bias;
        }
      }
      __syncthreads();

      // ---- spline: one (row, dim) task per thread ----
      {
        const float* P = &prm[srow * 100 + sjj * 23];
        float uw[8], uh[8], ud[7];
#pragma unroll
        for (int i = 0; i < 8; ++i) uw[i] = P[i];
#pragma unroll
        for (int i = 0; i < 8; ++i) uh[i] = P[8 + i];
#pragma unroll
        for (int i = 0; i < 7; ++i) ud[i] = P[16 + i];

        // softmax widths -> cumwidths
        float mw = uw[0];
#pragma unroll
        for (int i = 1; i < 8; ++i) mw = fmaxf(mw, uw[i]);
        float ew[8], sw = 0.f;
#pragma unroll
        for (int i = 0; i < 8; ++i) { ew[i] = __expf(uw[i] - mw); sw += ew[i]; }
        float invw = 1.f / sw;
        float cw[9]; cw[0] = -3.f;
        float accw = 0.f;
#pragma unroll
        for (int i = 0; i < 8; ++i) {
          accw += 0.001f + 0.992f * ew[i] * invw;
          cw[i + 1] = -3.f + 6.f * accw;
        }
        cw[8] = 3.f;
        float wd[8];
#pragma unroll
        for (int i = 0; i < 8; ++i) wd[i] = cw[i + 1] - cw[i];

        // softmax heights -> cumheights
        float mh = uh[0];
#pragma unroll
        for (int i = 1; i < 8; ++i) mh = fmaxf(mh, uh[i]);
        float eh[8], sh = 0.f;
#pragma unroll
        for (int i = 0; i < 8; ++i) { eh[i] = __expf(uh[i] - mh); sh += eh[i]; }
        float invh = 1.f / sh;
        float ch[9]; ch[0] = -3.f;
        float acch = 0.f;
#pragma unroll
        for (int i = 0; i < 8; ++i) {
          acch += 0.001f + 0.992f * eh[i] * invh;
          ch[i + 1] = -3.f + 6.f * acch;
        }
        ch[8] = 3.f;
        float ht[8];
#pragma unroll
        for (int i = 0; i < 8; ++i) ht[i] = ch[i + 1] - ch[i];

        // derivatives: branch-free softplus; boundary pad gives exactly 1.0
        float dd[9]; dd[0] = 1.f; dd[8] = 1.f;
#pragma unroll
        for (int i = 0; i < 7; ++i) {
          float u = ud[i];
          float sp = fmaxf(u, 0.f) + __logf(1.f + __expf(-fabsf(u)));
          dd[i + 1] = 0.001f + sp;
        }

        int jg = c * 4 + sjj;
        float xv = x2s[srow * 33 + jg];
        float xc = fminf(fmaxf(xv, -3.f), 3.f);

        int bin = 0;   // count of interior cumwidths <= x
#pragma unroll
        for (int i = 1; i < 8; ++i) bin += (xc >= cw[i]) ? 1 : 0;

        // gather via unrolled select chains (static indices -> registers)
        float in_cw = cw[0], in_w = wd[0], in_ch = ch[0], in_h = ht[0];
        float in_d = dd[0], in_d1 = dd[1];
#pragma unroll
        for (int i = 1; i < 8; ++i) {
          bool g = (bin >= i);
          in_cw = g ? cw[i] : in_cw;  in_w = g ? wd[i] : in_w;
          in_ch = g ? ch[i] : in_ch;  in_h = g ? ht[i] : in_h;
          in_d  = g ? dd[i] : in_d;   in_d1 = g ? dd[i + 1] : in_d1;
        }

        float dlt = in_h / in_w;
        float th = (xc - in_cw) / in_w;
        float om = 1.f - th;
        float t1 = th * om;
        float num = in_h * (dlt * th * th + in_d * t1);
        float den = dlt + (in_d + in_d1 - 2.f * dlt) * t1;
        float yo = in_ch + num / den;
        float dn = dlt * dlt * (in_d1 * th * th + 2.f * dlt * t1 + in_d * om * om);
        float ldv = __logf(dn / (den * den));   // fused: log(dn) - 2 log(den)
        bool inside = (xv >= -3.f) && (xv <= 3.f);
        out[(size_t)(row0 + srow) * 64 + 32 + jg] = inside ? yo : xv;
        ldp += inside ? ldv : 0.f;
      }
      __syncthreads();
    }

    // ---- log_det: quad reduce over sjj ----
    float tot = ldp;
    tot += __shfl_xor(tot, 1, 64);
    tot += __shfl_xor(tot, 2, 64);
    if ((tid & 3) == 0)
      out[(size_t)BATCH * 64 + row0 + srow] = tot;
  }
}

// ---------------------------------------------------------------------------
extern "C" void kernel_launch(void* const* d_in, const int* in_sizes, int n_in,
                              void* d_out, int out_size, void* d_ws, size_t ws_size,
                              hipStream_t stream) {
  const float* x  = (const float*)d_in[0];
  const float* W1 = (const float*)d_in[1];
  const float* b1 = (const float*)d_in[2];
  const float* W2 = (const float*)d_in[3];
  const float* b2 = (const float*)d_in[4];
  const float* W3 = (const float*)d_in[5];
  const float* b3 = (const float*)d_in[6];
  const float* W4 = (const float*)d_in[7];
  const float* b4 = (const float*)d_in[8];
  f16_t* wf = (f16_t*)d_ws;
  float* out = (float*)d_out;

  hipLaunchKernelGGL(convert_weights_kernel, dim3(66), dim3(256), 0, stream,
                     W1, W2, W3, W4, wf);
  hipLaunchKernelGGL(nsf_fused_kernel, dim3(NBLK), dim3(256), 0, stream,
                     x, b1, b2, b3, b4, wf, out);
}